// Round 9
// baseline (670.891 us; speedup 1.0000x reference)
//
#include <hip/hip_runtime.h>
#include <hip/hip_fp16.h>
#include <math.h>

#define BB 64
#define CC 512
#define DTT 1024
#define NNEG 53
#define MARGIN_ 0.2f
#define EPSV 1e-8f
#define LDB 132

typedef short s16x8 __attribute__((ext_vector_type(8)));
typedef float f32x4 __attribute__((ext_vector_type(4)));

__device__ __forceinline__ float bred_sum(float v, float* red, int tid, int nt) {
  red[tid] = v; __syncthreads();
  for (int s = nt >> 1; s > 0; s >>= 1) { if (tid < s) red[tid] += red[tid + s]; __syncthreads(); }
  float r = red[0]; __syncthreads();
  return r;
}
__device__ __forceinline__ float bred_max(float v, float* red, int tid, int nt) {
  red[tid] = v; __syncthreads();
  for (int s = nt >> 1; s > 0; s >>= 1) { if (tid < s) red[tid] = fmaxf(red[tid], red[tid + s]); __syncthreads(); }
  float r = red[0]; __syncthreads();
  return r;
}

// K1+Kprep fused: blocks 0..63 = sentence prep; blocks 64..1087 = iou->fp16 prep.
__global__ void k_sentprep(const float* __restrict__ sent, const float* __restrict__ iou,
                           float* __restrict__ Sn, float* __restrict__ SnT,
                           unsigned short* __restrict__ SnH, unsigned short* __restrict__ SnL,
                           float* __restrict__ SnSum, __half* __restrict__ L16) {
  int tid = threadIdx.x;
  if (blockIdx.x >= 64) {
    int g = ((blockIdx.x - 64) * 256 + tid) * 4;
    float4 x = *(const float4*)(iou + g);
    __half2 h0 = __floats2half2_rn(1.f - x.x, 1.f - x.y);
    __half2 h1 = __floats2half2_rn(1.f - x.z, 1.f - x.w);
    *(__half2*)(L16 + g) = h0;
    *(__half2*)(L16 + g + 2) = h1;
    return;
  }
  int b = blockIdx.x;
  __shared__ float red[256];
  float x0 = sent[b * CC + tid], x1 = sent[b * CC + tid + 256];
  float mean = bred_sum(x0 + x1, red, tid, 256) * (1.0f / CC);
  float s0 = x0 - mean, s1 = x1 - mean;
  float ss = bred_sum(s0 * s0 + s1 * s1, red, tid, 256);
  float nrm = fmaxf(sqrtf(ss), EPSV);
  float n0 = s0 / nrm, n1 = s1 / nrm;
  Sn[b * CC + tid] = n0; Sn[b * CC + tid + 256] = n1;
  SnT[tid * BB + b] = n0; SnT[(tid + 256) * BB + b] = n1;
  unsigned u0 = __float_as_uint(n0), u1 = __float_as_uint(n1);
  SnH[b * CC + tid] = (unsigned short)(u0 >> 16);
  SnH[b * CC + tid + 256] = (unsigned short)(u1 >> 16);
  float l0 = n0 - __uint_as_float(u0 & 0xFFFF0000u);
  float l1 = n1 - __uint_as_float(u1 & 0xFFFF0000u);
  SnL[b * CC + tid] = (unsigned short)(__float_as_uint(l0) >> 16);
  SnL[b * CC + tid + 256] = (unsigned short)(__float_as_uint(l1) >> 16);
  float sn = bred_sum(n0 + n1, red, tid, 256);
  if (tid == 0) SnSum[b] = sn;
}

// KS: sim row i; 256 threads = (j, c-quarter); coalesced via SnT; rank logic on 64.
__global__ void k_sim(const float* __restrict__ Sn, const float* __restrict__ SnT,
                      int* __restrict__ nn_idx, int* __restrict__ negidx,
                      float* __restrict__ nnsim) {
  int i = blockIdx.x, tid = threadIdx.x;
  int j = tid & 63, cq = tid >> 6;
  __shared__ float part[4][68];
  __shared__ float srow[BB];
  float acc = 0.f;
  const float* si = Sn + i * CC + cq * 128;
  const float* st = SnT + (size_t)(cq * 128) * BB + j;
#pragma unroll 8
  for (int c = 0; c < 128; ++c) acc = fmaf(si[c], st[(size_t)c * BB], acc);
  part[cq][j] = acc;
  __syncthreads();
  if (tid < 64) srow[tid] = part[0][tid] + part[1][tid] + part[2][tid] + part[3][tid];
  __syncthreads();
  if (tid < 64) {
    float mv = srow[tid];
    int rank = 0;
    for (int k = 0; k < BB; ++k) {
      float vk = srow[k];
      if (vk > mv || (vk == mv && k < tid)) rank++;
    }
    if (rank == 1) { nn_idx[i] = tid; nnsim[i] = mv; }
    if (rank >= 6 && rank < 59) negidx[i * NNEG + rank - 6] = tid;
  }
}

// K3: split-bf16 MFMA GEMM, double-buffered LDS (measured-best, unchanged).
__global__ __launch_bounds__(256) void k_cross(const float* __restrict__ videos,
    const unsigned short* __restrict__ SnH, const unsigned short* __restrict__ SnL,
    const float* __restrict__ SnSum, const float* __restrict__ mask,
    float* __restrict__ cross, float* __restrict__ meanv, float* __restrict__ normv) {
  __shared__ unsigned int BH[2][16][LDB];
  __shared__ unsigned int BL[2][16][LDB];
  __shared__ float SnSum_s[64];
  __shared__ float mb_s[128];
  __shared__ float inv_s[128];

  int tid = threadIdx.x;
  int j = blockIdx.x >> 3;
  int p0 = (blockIdx.x & 7) << 7;
  int lane = tid & 63;
  int wv = tid >> 6;
  int row = lane & 15;
  int g = lane >> 4;
  int g8 = g << 3;
  int pA = wv << 5;

  int kp = tid >> 4;
  int pb = (tid & 15) << 3;

  const float* vbase = videos + ((size_t)j * CC) * DTT + p0;

  f32x4 acc[4][2];
#pragma unroll
  for (int a = 0; a < 4; ++a)
#pragma unroll
    for (int pf = 0; pf < 2; ++pf)
#pragma unroll
      for (int r = 0; r < 4; ++r) acc[a][pf][r] = 0.f;

  float sacc[8], ssacc[8];
#pragma unroll
  for (int q = 0; q < 8; ++q) { sacc[q] = 0.f; ssacc[q] = 0.f; }

  const float* pr = vbase + (size_t)(2 * kp) * DTT + pb;
  float4 f0 = *(const float4*)(pr);
  float4 f1 = *(const float4*)(pr + 4);
  float4 f2 = *(const float4*)(pr + DTT);
  float4 f3 = *(const float4*)(pr + DTT + 4);

#pragma unroll
  for (int t = 0; t < 16; ++t) {
    int kc = t * 32;
    int cb = t & 1;
    s16x8 AH[4], AL[4];
#pragma unroll
    for (int a = 0; a < 4; ++a) {
      int off = (a * 16 + row) * CC + kc + g8;
      AH[a] = *(const s16x8*)(SnH + off);
      AL[a] = *(const s16x8*)(SnL + off);
    }
    {
      float xe[8] = {f0.x, f0.y, f0.z, f0.w, f1.x, f1.y, f1.z, f1.w};
      float xo[8] = {f2.x, f2.y, f2.z, f2.w, f3.x, f3.y, f3.z, f3.w};
      unsigned int hw[8], lw[8];
#pragma unroll
      for (int q = 0; q < 8; ++q) {
        unsigned ue = __float_as_uint(xe[q]);
        unsigned uo = __float_as_uint(xo[q]);
        hw[q] = (ue >> 16) | (uo & 0xFFFF0000u);
        float el = xe[q] - __uint_as_float(ue & 0xFFFF0000u);
        float ol = xo[q] - __uint_as_float(uo & 0xFFFF0000u);
        lw[q] = (__float_as_uint(el) >> 16) | (__float_as_uint(ol) & 0xFFFF0000u);
        sacc[q] += xe[q] + xo[q];
        ssacc[q] = fmaf(xe[q], xe[q], ssacc[q]);
        ssacc[q] = fmaf(xo[q], xo[q], ssacc[q]);
      }
      *(uint4*)&BH[cb][kp][pb]     = make_uint4(hw[0], hw[1], hw[2], hw[3]);
      *(uint4*)&BH[cb][kp][pb + 4] = make_uint4(hw[4], hw[5], hw[6], hw[7]);
      *(uint4*)&BL[cb][kp][pb]     = make_uint4(lw[0], lw[1], lw[2], lw[3]);
      *(uint4*)&BL[cb][kp][pb + 4] = make_uint4(lw[4], lw[5], lw[6], lw[7]);
    }
    if (t + 1 < 16) {
      const float* pn = vbase + (size_t)((t + 1) * 32 + 2 * kp) * DTT + pb;
      f0 = *(const float4*)(pn);
      f1 = *(const float4*)(pn + 4);
      f2 = *(const float4*)(pn + DTT);
      f3 = *(const float4*)(pn + DTT + 4);
    }
    __syncthreads();
#pragma unroll
    for (int pf = 0; pf < 2; ++pf) {
      int p = pA + pf * 16 + row;
      int kpb = g << 2;
      union { unsigned int u[4]; s16x8 v; } bh, bl;
      bh.u[0] = BH[cb][kpb][p]; bh.u[1] = BH[cb][kpb + 1][p];
      bh.u[2] = BH[cb][kpb + 2][p]; bh.u[3] = BH[cb][kpb + 3][p];
      bl.u[0] = BL[cb][kpb][p]; bl.u[1] = BL[cb][kpb + 1][p];
      bl.u[2] = BL[cb][kpb + 2][p]; bl.u[3] = BL[cb][kpb + 3][p];
#pragma unroll
      for (int a = 0; a < 4; ++a) {
        acc[a][pf] = __builtin_amdgcn_mfma_f32_16x16x32_bf16(AH[a], bh.v, acc[a][pf], 0, 0, 0);
        acc[a][pf] = __builtin_amdgcn_mfma_f32_16x16x32_bf16(AH[a], bl.v, acc[a][pf], 0, 0, 0);
        acc[a][pf] = __builtin_amdgcn_mfma_f32_16x16x32_bf16(AL[a], bh.v, acc[a][pf], 0, 0, 0);
      }
    }
  }

  float (*Sred)[LDB] = (float(*)[LDB])&BH[0][0][0];
  float (*SSred)[LDB] = (float(*)[LDB])&BL[0][0][0];
#pragma unroll
  for (int q = 0; q < 8; ++q) { Sred[kp][pb + q] = sacc[q]; SSred[kp][pb + q] = ssacc[q]; }
  if (tid < 64) SnSum_s[tid] = SnSum[tid];
  __syncthreads();
  if (tid < 128) {
    float s = 0.f, ss = 0.f;
#pragma unroll
    for (int k = 0; k < 16; ++k) { s += Sred[k][tid]; ss += SSred[k][tid]; }
    float mb = s * (1.0f / CC);
    float var = ss - s * mb;
    float nrm = fmaxf(sqrtf(fmaxf(var, 0.f)), EPSV);
    meanv[j * DTT + p0 + tid] = mb;
    normv[j * DTT + p0 + tid] = nrm;
    mb_s[tid] = mb;
    inv_s[tid] = 1.f / nrm;
  }
  __syncthreads();

#pragma unroll
  for (int pf = 0; pf < 2; ++pf) {
    int p = pA + pf * 16 + row;
    float mb = mb_s[p], inv = inv_s[p];
    float mk = mask[p0 + p];
#pragma unroll
    for (int a = 0; a < 4; ++a) {
#pragma unroll
      for (int r = 0; r < 4; ++r) {
        int i = a * 16 + (g << 2) + r;
        float val = (acc[a][pf][r] - mb * SnSum_s[i]) * inv;
        if (mk == 0.f) val = -INFINITY;
        cross[((size_t)i * BB + j) * DTT + p0 + p] = val;
      }
    }
  }
}

// K4: self_score -> pmap, softmax -> w, wm; also zero the vp accumulators.
__global__ void k_softmax_w(const float* __restrict__ cross, const float* __restrict__ meanv,
                            float* __restrict__ pmap, float* __restrict__ w, float* __restrict__ wm,
                            float* __restrict__ vpsum_a, float* __restrict__ vpss_a) {
  int b = blockIdx.x, tid = threadIdx.x;
  __shared__ float red[256];
  if (tid == 0) { vpsum_a[b] = 0.f; vpss_a[b] = 0.f; }
  const float* row = cross + ((size_t)b * BB + b) * DTT;
  float v[4]; float mx = -INFINITY;
#pragma unroll
  for (int q = 0; q < 4; ++q) {
    v[q] = row[q * 256 + tid];
    pmap[b * DTT + q * 256 + tid] = v[q];
    mx = fmaxf(mx, v[q]);
  }
  mx = bred_max(mx, red, tid, 256);
  float e[4]; float se = 0.f;
#pragma unroll
  for (int q = 0; q < 4; ++q) { e[q] = expf(v[q] - mx); se += e[q]; }
  se = bred_sum(se, red, tid, 256);
  float inv = 1.f / se;
  float wmacc = 0.f;
#pragma unroll
  for (int q = 0; q < 4; ++q) {
    float wv = e[q] * inv;
    w[b * DTT + q * 256 + tid] = wv;
    wmacc += wv * meanv[b * DTT + q * 256 + tid];
  }
  wmacc = bred_sum(wmacc, red, tid, 256);
  if (tid == 0) wm[b] = wmacc;
}

// K5: video_pos + per-b sum/sumsq accumulation (replaces k_vpnorm).
__global__ void k_vpos(const float* __restrict__ videos, const float* __restrict__ w,
                       const float* __restrict__ wm, float* __restrict__ vp,
                       float* __restrict__ vpsum_a, float* __restrict__ vpss_a) {
  int wid = (blockIdx.x * 256 + threadIdx.x) >> 6;
  int lane = threadIdx.x & 63;
  int b = wid >> 9, c = wid & 511;
  const float4* vb = (const float4*)(videos + (size_t)(b * CC + c) * DTT) + lane * 4;
  const float4* wb = (const float4*)(w + b * DTT) + lane * 4;
  float acc = 0.f;
#pragma unroll
  for (int q = 0; q < 4; ++q) {
    float4 x = vb[q], y = wb[q];
    acc += x.x * y.x + x.y * y.y + x.z * y.z + x.w * y.w;
  }
#pragma unroll
  for (int off = 32; off > 0; off >>= 1) acc += __shfl_xor(acc, off);
  if (lane == 0) {
    float val = acc - wm[b];
    vp[b * CC + c] = val;
    atomicAdd(&vpsum_a[b], val);
    atomicAdd(&vpss_a[b], val * val);
  }
}

// K6: vsim logits — 16-deep load batching; vpn computed from vpss.
__global__ void k_vsim_logits(const float* __restrict__ videos, const float* __restrict__ vp,
    const float* __restrict__ vpss_a, const float* __restrict__ vpsum_a, const int* __restrict__ nn_idx,
    const float* __restrict__ meanv, const float* __restrict__ normv, float* __restrict__ vslog) {
  int gid = blockIdx.x * 256 + threadIdx.x;
  int b = gid >> 10, p = gid & 1023;
  int nn = nn_idx[b];
  const float* base = videos + (size_t)nn * CC * DTT + p;
  const float* vpr = vp + b * CC;
  float acc = 0.f;
#pragma unroll 1
  for (int c0 = 0; c0 < CC; c0 += 16) {
    float v[16];
#pragma unroll
    for (int u = 0; u < 16; ++u) v[u] = base[(size_t)(c0 + u) * DTT];
#pragma unroll
    for (int u = 0; u < 16; ++u) acc = fmaf(vpr[c0 + u], v[u], acc);
  }
  acc -= meanv[nn * DTT + p] * vpsum_a[b];
  float vpn = fmaxf(sqrtf(vpss_a[b]), EPSV);
  vslog[gid] = acc / (vpn * normv[nn * DTT + p]);
}

// K7: softmax(vslog) in-place -> vsim ; svp, svn
__global__ void k_softmax_vsim(float* __restrict__ vslog, const int* __restrict__ nn_idx,
    const float* __restrict__ meanv, const float* __restrict__ mask,
    float* __restrict__ svp, float* __restrict__ svn) {
  int b = blockIdx.x, tid = threadIdx.x;
  __shared__ float red[256];
  int nn = nn_idx[b];
  float v[4]; float mx = -INFINITY;
#pragma unroll
  for (int q = 0; q < 4; ++q) { v[q] = vslog[b * DTT + q * 256 + tid]; mx = fmaxf(mx, v[q]); }
  mx = bred_max(mx, red, tid, 256);
  float e[4]; float se = 0.f;
#pragma unroll
  for (int q = 0; q < 4; ++q) { e[q] = expf(v[q] - mx); se += e[q]; }
  se = bred_sum(se, red, tid, 256);
  float inv = 1.f / se;
  float sp = 0.f, sn2 = 0.f;
#pragma unroll
  for (int q = 0; q < 4; ++q) {
    int p = q * 256 + tid;
    float vs = e[q] * inv;
    vslog[b * DTT + p] = vs;
    float mm = meanv[nn * DTT + p];
    sp += vs * mm;
    sn2 += (1.f - vs) * mask[p] * mm;
  }
  sp = bred_sum(sp, red, tid, 256);
  sn2 = bred_sum(sn2, red, tid, 256);
  if (tid == 0) { svp[b] = sp; svn[b] = sn2; }
}

// K8: p_v and n_v  (one wave per (b,c))
__global__ void k_pvnv(const float* __restrict__ videos, const float* __restrict__ vsim,
    const int* __restrict__ nn_idx, const float* __restrict__ mask,
    const float* __restrict__ svp, const float* __restrict__ svn, const int* __restrict__ vn_p,
    float* __restrict__ pv, float* __restrict__ nv) {
  int wid = (blockIdx.x * 256 + threadIdx.x) >> 6;
  int lane = threadIdx.x & 63;
  int b = wid >> 9, c = wid & 511;
  int nn = nn_idx[b];
  const float4* vb = (const float4*)(videos + (size_t)(nn * CC + c) * DTT) + lane * 4;
  const float4* vs4 = (const float4*)(vsim + b * DTT) + lane * 4;
  const float4* m4 = ((const float4*)mask) + lane * 4;
  float ap = 0.f, an = 0.f;
#pragma unroll
  for (int q = 0; q < 4; ++q) {
    float4 x = vb[q], s = vs4[q], m = m4[q];
    ap += x.x * s.x + x.y * s.y + x.z * s.z + x.w * s.w;
    an += x.x * (1.f - s.x) * m.x + x.y * (1.f - s.y) * m.y + x.z * (1.f - s.z) * m.z + x.w * (1.f - s.w) * m.w;
  }
#pragma unroll
  for (int off = 32; off > 0; off >>= 1) { ap += __shfl_xor(ap, off); an += __shfl_xor(an, off); }
  if (lane == 0) {
    float kd = (float)(*vn_p - 1);
    pv[b * CC + c] = ap - svp[b];
    nv[b * CC + c] = (an - svn[b]) / kd;
  }
}

// Kvas+Kcrov fused: vas phase (coalesced SnT gathers) then crov phase.
__global__ void k_vascrov(const float* __restrict__ vp, const float* __restrict__ vpss_a,
                          const float* __restrict__ SnT, const int* __restrict__ negidx,
                          const float* __restrict__ pv, const float* __restrict__ nv,
                          const float* __restrict__ nnsim,
                          float* __restrict__ vasrow, float* __restrict__ crovrow) {
  int i = blockIdx.x, tid = threadIdx.x;  // 256
  int t = tid & 63, cq = tid >> 6;
  __shared__ float part[4][68];
  __shared__ float redv[64];
  __shared__ float red[256];
  float invn = 1.f / fmaxf(sqrtf(vpss_a[i]), EPSV);
  // --- vas phase ---
  {
    int nj = (t < NNEG) ? negidx[i * NNEG + t] : i;  // t==63 row computes pos
    float acc = 0.f;
    const float* vpr = vp + i * CC + cq * 128;
    const float* st = SnT + (size_t)(cq * 128) * BB + nj;
#pragma unroll 8
    for (int c = 0; c < 128; ++c) acc = fmaf(vpr[c], st[(size_t)c * BB], acc);
    part[cq][t] = acc;
    __syncthreads();
    if (tid < 64) redv[tid] = part[0][tid] + part[1][tid] + part[2][tid] + part[3][tid];
    __syncthreads();
    float pos = redv[63] * invn;
    float contrib = (tid < NNEG) ? fmaxf(MARGIN_ + redv[tid] * invn - pos, 0.f) : 0.f;
    float s = bred_sum(contrib, red, tid, 256);
    if (tid == 0) vasrow[i] = s / (float)NNEG;
  }
  // --- crov phase ---
  {
    float dp = 0.f, pp = 0.f, dn = 0.f, nn2 = 0.f;
    for (int c = tid; c < CC; c += 256) {
      float a = vp[i * CC + c], x = pv[i * CC + c], y = nv[i * CC + c];
      dp += a * x; pp += x * x; dn += a * y; nn2 += y * y;
    }
    dp = bred_sum(dp, red, tid, 256);
    pp = bred_sum(pp, red, tid, 256);
    dn = bred_sum(dn, red, tid, 256);
    nn2 = bred_sum(nn2, red, tid, 256);
    if (tid == 0) {
      float cosp = dp * invn / fmaxf(sqrtf(pp), EPSV);
      float cosn = dn * invn / fmaxf(sqrtf(nn2), EPSV);
      float crov = fmaxf(MARGIN_ + cosn - cosp, 0.f);
      crovrow[i] = (nnsim[i] > 0.9f) ? crov : 0.f;
    }
  }
}

// K9 fused: block per (i,j). Wave 0: radix select + rank-order into LDS (ti, tv).
// Then all 4 waves: decay products (shuffle version) + wave-0 softmax score.
// No ordi/ordv global roundtrip.
__global__ __launch_bounds__(256) void k_seldecay(const float* __restrict__ cross,
    const __half* __restrict__ L16, const float* __restrict__ lam_p,
    const int* __restrict__ vn_p, float* __restrict__ scores) {
  __shared__ unsigned int hist[256];
  __shared__ unsigned int sel[128];
  __shared__ unsigned int selk[128];
  __shared__ unsigned int cnt;
  __shared__ unsigned ti[128];
  __shared__ float tv[128];
  __shared__ float dks[128];
  int ij = blockIdx.x, tid = threadIdx.x;
  int wv = tid >> 6, lane = tid & 63;
  int K = *vn_p; if (K > 128) K = 128;
  float lam = *lam_p;

  if (wv == 0) {
    const float* row = cross + (size_t)ij * DTT;
    unsigned int v[16];
#pragma unroll
    for (int q = 0; q < 16; ++q) {
      unsigned u = __float_as_uint(row[q * 64 + lane]);
      v[q] = (u & 0x80000000u) ? ~u : (u | 0x80000000u);
    }
    if (lane == 0) cnt = 0u;
    __builtin_amdgcn_wave_barrier();

    unsigned prefix = 0u, pmask = 0u;
    int remaining = K;
    for (int shift = 24; shift >= 0; shift -= 8) {
#pragma unroll
      for (int q = 0; q < 4; ++q) hist[lane * 4 + q] = 0u;
      __builtin_amdgcn_wave_barrier();
#pragma unroll
      for (int q = 0; q < 16; ++q) {
        if ((v[q] & pmask) == prefix)
          atomicAdd(&hist[(v[q] >> shift) & 255u], 1u);
      }
      __builtin_amdgcn_wave_barrier();
      unsigned c0 = hist[lane * 4], c1 = hist[lane * 4 + 1];
      unsigned c2 = hist[lane * 4 + 2], c3 = hist[lane * 4 + 3];
      unsigned s = c0 + c1 + c2 + c3;
      unsigned inc = s;
#pragma unroll
      for (int off = 1; off < 64; off <<= 1) {
        unsigned t = __shfl_down(inc, off);
        if (lane + off < 64) inc += t;
      }
      unsigned exc = inc - s;
      bool found = (exc < (unsigned)remaining) && (inc >= (unsigned)remaining);
      unsigned long long bmask = __ballot(found);
      int winner = (int)(__ffsll((unsigned long long)bmask) - 1);
      unsigned packed = 0u;
      if (found) {
        unsigned c = exc;
        unsigned cc[4] = {c0, c1, c2, c3};
        int d = lane * 4;
#pragma unroll
        for (int q = 3; q >= 0; --q) {
          if (c + cc[q] >= (unsigned)remaining) { d = lane * 4 + q; break; }
          c += cc[q];
        }
        packed = ((unsigned)d << 16) | (unsigned)(remaining - (int)c);
      }
      packed = __shfl(packed, winner);
      prefix |= (packed >> 16) << shift;
      remaining = (int)(packed & 0xFFFFu);
      pmask |= 255u << shift;
    }

#pragma unroll
    for (int q = 0; q < 16; ++q) {
      if (v[q] > prefix) {
        unsigned pos = atomicAdd(&cnt, 1u);
        sel[pos] = (unsigned)(q * 64 + lane);
        selk[pos] = v[q];
      }
    }
    __builtin_amdgcn_wave_barrier();
    {
      int base = K - remaining;
      int last = -1;
      for (int t = 0; t < remaining; ++t) {
        int mymin = 0x7FFFFFFF;
#pragma unroll
        for (int q = 0; q < 16; ++q) {
          int idx = q * 64 + lane;
          if (v[q] == prefix && idx > last && idx < mymin) mymin = idx;
        }
#pragma unroll
        for (int off = 32; off > 0; off >>= 1) mymin = min(mymin, __shfl_xor(mymin, off));
        if (lane == 0) { sel[base + t] = (unsigned)mymin; selk[base + t] = prefix; }
        last = mymin;
      }
    }
    __builtin_amdgcn_wave_barrier();

    // rank-by-count: (mono desc, idx asc); write rank-ordered to LDS
    for (int e = lane; e < K; e += 64) {
      unsigned myidx = sel[e], myk = selk[e];
      int rank = 0;
      for (int m = 0; m < K; ++m) {
        unsigned ok = selk[m];
        rank += (ok > myk || (ok == myk && sel[m] < myidx)) ? 1 : 0;
      }
      unsigned u = (myk & 0x80000000u) ? (myk & 0x7FFFFFFFu) : ~myk;
      ti[rank] = myidx;
      tv[rank] = __uint_as_float(u);
    }
  }
  __syncthreads();

  // decay phase (all 4 waves), shuffle reduce — measured-good version
  for (int r = wv; r < K; r += 4) {
    const __half* irow = L16 + (size_t)ti[r] * DTT;
    float f = 1.f;
    if (lane < r && lane < 64) f = __half2float(irow[ti[lane]]);
    float prod = f;
#pragma unroll
    for (int off = 32; off > 0; off >>= 1) prod *= __shfl_xor(prod, off);
    if (r > 64 && prod > 1e-14f) {
      float f2 = 1.f;
      int m = 64 + lane;
      if (m < r) f2 = __half2float(irow[ti[m]]);
#pragma unroll
      for (int off = 32; off > 0; off >>= 1) f2 *= __shfl_xor(f2, off);
      prod *= f2;
    }
    if (lane == 0) dks[r] = prod;
  }
  __syncthreads();

  if (wv == 0) {
    bool okA = (lane < K), okB = (lane + 64 < K);
    float vA = okA ? tv[lane] : 0.f;
    float vB = okB ? tv[lane + 64] : 0.f;
    float mx = fmaxf(okA ? lam * vA : -INFINITY, okB ? lam * vB : -INFINITY);
#pragma unroll
    for (int off = 32; off > 0; off >>= 1) mx = fmaxf(mx, __shfl_xor(mx, off));
    float eA = okA ? expf(lam * vA - mx) : 0.f;
    float eB = okB ? expf(lam * vB - mx) : 0.f;
    float se = eA + eB;
    float sc = (okA ? eA * dks[lane] * vA : 0.f) + (okB ? eB * dks[lane + 64] * vB : 0.f);
#pragma unroll
    for (int off = 32; off > 0; off >>= 1) {
      se += __shfl_xor(se, off);
      sc += __shfl_xor(sc, off);
    }
    if (lane == 0) scores[ij] = sc / se;
  }
}

// Kfinal: hinge maxima + loss
__global__ void k_final(const float* __restrict__ scores, const float* __restrict__ vasrow,
                        const float* __restrict__ crovrow, float* __restrict__ out) {
  int tid = threadIdx.x;  // 64 threads
  __shared__ float sm[BB * BB];
  __shared__ float red[64];
  for (int q = tid; q < BB * BB; q += 64) sm[q] = scores[q];
  __syncthreads();
  float di = sm[tid * BB + tid];
  float rowmax = 0.f, colmax = 0.f;
  for (int k = 0; k < BB; ++k) {
    if (k != tid) {
      rowmax = fmaxf(rowmax, fmaxf(MARGIN_ + sm[tid * BB + k] - di, 0.f));
      colmax = fmaxf(colmax, fmaxf(MARGIN_ + sm[k * BB + tid] - di, 0.f));
    }
  }
  float total = bred_sum(rowmax + colmax + vasrow[tid] + crovrow[tid], red, tid, 64);
  if (tid == 0) out[0] = total * (1.0f / BB);
}

extern "C" void kernel_launch(void* const* d_in, const int* in_sizes, int n_in,
                              void* d_out, int out_size, void* d_ws, size_t ws_size,
                              hipStream_t stream) {
  const float* videos = (const float*)d_in[0];
  const float* sentences = (const float*)d_in[1];
  const float* lam = (const float*)d_in[2];
  const float* mask = (const float*)d_in[3];
  const int* valid_num = (const int*)d_in[4];
  const float* iou_maps = (const float*)d_in[5];
  float* out = (float*)d_out;
  float* pmap = out + 1;

  float* ws = (float*)d_ws;
  float* Sn = ws;                      // 32768
  float* SnT = Sn + 32768;             // 32768
  float* SnSum = SnT + 32768;          // 64
  float* meanv = SnSum + 64;           // 65536
  float* normv = meanv + 65536;        // 65536
  float* cross = normv + 65536;        // 4194304
  float* w = cross + 4194304;          // 65536
  float* wm = w + 65536;               // 64
  float* vp = wm + 64;                 // 32768
  float* vpss_a = vp + 32768;          // 64 (sum of squares accumulator)
  float* vpsum_a = vpss_a + 64;        // 64 (sum accumulator)
  float* nnsim = vpsum_a + 64;         // 64
  float* vslog = nnsim + 64;           // 65536 (becomes vsim in-place)
  float* svp = vslog + 65536;          // 64
  float* svn = svp + 64;               // 64
  float* pvb = svn + 64;               // 32768
  float* nvb = pvb + 32768;            // 32768
  float* vasrow = nvb + 32768;         // 64
  float* crovrow = vasrow + 64;        // 64
  float* scores = crovrow + 64;        // 4096
  int* nn_idx = (int*)(scores + 4096); // 64
  int* negidx = nn_idx + 64;           // 3392
  unsigned* ordi_unused = (unsigned*)(negidx + 3392);  // 524288 (slot kept)
  float* ordv_unused = (float*)(ordi_unused + 524288); // 524288 (slot kept)
  __half* L16 = (__half*)(ordv_unused + 524288);       // 1048576 halfs = 2MB
  unsigned short* SnH16 = (unsigned short*)(L16 + 1048576);  // 32768 u16
  unsigned short* SnL16 = SnH16 + 32768;                     // 32768 u16

  k_sentprep<<<1088, 256, 0, stream>>>(sentences, iou_maps, Sn, SnT, SnH16, SnL16, SnSum, L16);
  k_sim<<<64, 256, 0, stream>>>(Sn, SnT, nn_idx, negidx, nnsim);
  k_cross<<<512, 256, 0, stream>>>(videos, SnH16, SnL16, SnSum, mask, cross, meanv, normv);
  k_softmax_w<<<64, 256, 0, stream>>>(cross, meanv, pmap, w, wm, vpsum_a, vpss_a);
  k_vpos<<<8192, 256, 0, stream>>>(videos, w, wm, vp, vpsum_a, vpss_a);
  k_vsim_logits<<<256, 256, 0, stream>>>(videos, vp, vpss_a, vpsum_a, nn_idx, meanv, normv, vslog);
  k_softmax_vsim<<<64, 256, 0, stream>>>(vslog, nn_idx, meanv, mask, svp, svn);
  k_pvnv<<<8192, 256, 0, stream>>>(videos, vslog, nn_idx, mask, svp, svn, valid_num, pvb, nvb);
  k_vascrov<<<64, 256, 0, stream>>>(vp, vpss_a, SnT, negidx, pvb, nvb, nnsim, vasrow, crovrow);
  k_seldecay<<<4096, 256, 0, stream>>>(cross, L16, lam, valid_num, scores);
  k_final<<<1, 64, 0, stream>>>(scores, vasrow, crovrow, out);
}

// Round 10
// 418.216 us; speedup vs baseline: 1.6042x; 1.6042x over previous
//
#include <hip/hip_runtime.h>
#include <hip/hip_fp16.h>
#include <math.h>

#define BB 64
#define CC 512
#define DTT 1024
#define NNEG 53
#define MARGIN_ 0.2f
#define EPSV 1e-8f
#define LDB 132

typedef short s16x8 __attribute__((ext_vector_type(8)));
typedef float f32x4 __attribute__((ext_vector_type(4)));

__device__ __forceinline__ float bred_sum(float v, float* red, int tid, int nt) {
  red[tid] = v; __syncthreads();
  for (int s = nt >> 1; s > 0; s >>= 1) { if (tid < s) red[tid] += red[tid + s]; __syncthreads(); }
  float r = red[0]; __syncthreads();
  return r;
}
__device__ __forceinline__ float bred_max(float v, float* red, int tid, int nt) {
  red[tid] = v; __syncthreads();
  for (int s = nt >> 1; s > 0; s >>= 1) { if (tid < s) red[tid] = fmaxf(red[tid], red[tid + s]); __syncthreads(); }
  float r = red[0]; __syncthreads();
  return r;
}

// K1+Kprep fused: blocks 0..63 = sentence prep; blocks 64..1087 = iou->fp16 prep.
__global__ void k_sentprep(const float* __restrict__ sent, const float* __restrict__ iou,
                           float* __restrict__ Sn, float* __restrict__ SnT,
                           unsigned short* __restrict__ SnH, unsigned short* __restrict__ SnL,
                           float* __restrict__ SnSum, __half* __restrict__ L16) {
  int tid = threadIdx.x;
  if (blockIdx.x >= 64) {
    int g = ((blockIdx.x - 64) * 256 + tid) * 4;
    float4 x = *(const float4*)(iou + g);
    __half2 h0 = __floats2half2_rn(1.f - x.x, 1.f - x.y);
    __half2 h1 = __floats2half2_rn(1.f - x.z, 1.f - x.w);
    *(__half2*)(L16 + g) = h0;
    *(__half2*)(L16 + g + 2) = h1;
    return;
  }
  int b = blockIdx.x;
  __shared__ float red[256];
  float x0 = sent[b * CC + tid], x1 = sent[b * CC + tid + 256];
  float mean = bred_sum(x0 + x1, red, tid, 256) * (1.0f / CC);
  float s0 = x0 - mean, s1 = x1 - mean;
  float ss = bred_sum(s0 * s0 + s1 * s1, red, tid, 256);
  float nrm = fmaxf(sqrtf(ss), EPSV);
  float n0 = s0 / nrm, n1 = s1 / nrm;
  Sn[b * CC + tid] = n0; Sn[b * CC + tid + 256] = n1;
  SnT[tid * BB + b] = n0; SnT[(tid + 256) * BB + b] = n1;
  unsigned u0 = __float_as_uint(n0), u1 = __float_as_uint(n1);
  SnH[b * CC + tid] = (unsigned short)(u0 >> 16);
  SnH[b * CC + tid + 256] = (unsigned short)(u1 >> 16);
  float l0 = n0 - __uint_as_float(u0 & 0xFFFF0000u);
  float l1 = n1 - __uint_as_float(u1 & 0xFFFF0000u);
  SnL[b * CC + tid] = (unsigned short)(__float_as_uint(l0) >> 16);
  SnL[b * CC + tid + 256] = (unsigned short)(__float_as_uint(l1) >> 16);
  float sn = bred_sum(n0 + n1, red, tid, 256);
  if (tid == 0) SnSum[b] = sn;
}

// KS: sim row i; 256 threads = (j, c-quarter); coalesced via SnT; rank logic on 64.
__global__ void k_sim(const float* __restrict__ Sn, const float* __restrict__ SnT,
                      int* __restrict__ nn_idx, int* __restrict__ negidx,
                      float* __restrict__ nnsim) {
  int i = blockIdx.x, tid = threadIdx.x;
  int j = tid & 63, cq = tid >> 6;
  __shared__ float part[4][68];
  __shared__ float srow[BB];
  float acc = 0.f;
  const float* si = Sn + i * CC + cq * 128;
  const float* st = SnT + (size_t)(cq * 128) * BB + j;
#pragma unroll 8
  for (int c = 0; c < 128; ++c) acc = fmaf(si[c], st[(size_t)c * BB], acc);
  part[cq][j] = acc;
  __syncthreads();
  if (tid < 64) srow[tid] = part[0][tid] + part[1][tid] + part[2][tid] + part[3][tid];
  __syncthreads();
  if (tid < 64) {
    float mv = srow[tid];
    int rank = 0;
    for (int k = 0; k < BB; ++k) {
      float vk = srow[k];
      if (vk > mv || (vk == mv && k < tid)) rank++;
    }
    if (rank == 1) { nn_idx[i] = tid; nnsim[i] = mv; }
    if (rank >= 6 && rank < 59) negidx[i * NNEG + rank - 6] = tid;
  }
}

// K3: split-bf16 MFMA GEMM, double-buffered LDS (measured-best, unchanged).
__global__ __launch_bounds__(256) void k_cross(const float* __restrict__ videos,
    const unsigned short* __restrict__ SnH, const unsigned short* __restrict__ SnL,
    const float* __restrict__ SnSum, const float* __restrict__ mask,
    float* __restrict__ cross, float* __restrict__ meanv, float* __restrict__ normv) {
  __shared__ unsigned int BH[2][16][LDB];
  __shared__ unsigned int BL[2][16][LDB];
  __shared__ float SnSum_s[64];
  __shared__ float mb_s[128];
  __shared__ float inv_s[128];

  int tid = threadIdx.x;
  int j = blockIdx.x >> 3;
  int p0 = (blockIdx.x & 7) << 7;
  int lane = tid & 63;
  int wv = tid >> 6;
  int row = lane & 15;
  int g = lane >> 4;
  int g8 = g << 3;
  int pA = wv << 5;

  int kp = tid >> 4;
  int pb = (tid & 15) << 3;

  const float* vbase = videos + ((size_t)j * CC) * DTT + p0;

  f32x4 acc[4][2];
#pragma unroll
  for (int a = 0; a < 4; ++a)
#pragma unroll
    for (int pf = 0; pf < 2; ++pf)
#pragma unroll
      for (int r = 0; r < 4; ++r) acc[a][pf][r] = 0.f;

  float sacc[8], ssacc[8];
#pragma unroll
  for (int q = 0; q < 8; ++q) { sacc[q] = 0.f; ssacc[q] = 0.f; }

  const float* pr = vbase + (size_t)(2 * kp) * DTT + pb;
  float4 f0 = *(const float4*)(pr);
  float4 f1 = *(const float4*)(pr + 4);
  float4 f2 = *(const float4*)(pr + DTT);
  float4 f3 = *(const float4*)(pr + DTT + 4);

#pragma unroll
  for (int t = 0; t < 16; ++t) {
    int kc = t * 32;
    int cb = t & 1;
    s16x8 AH[4], AL[4];
#pragma unroll
    for (int a = 0; a < 4; ++a) {
      int off = (a * 16 + row) * CC + kc + g8;
      AH[a] = *(const s16x8*)(SnH + off);
      AL[a] = *(const s16x8*)(SnL + off);
    }
    {
      float xe[8] = {f0.x, f0.y, f0.z, f0.w, f1.x, f1.y, f1.z, f1.w};
      float xo[8] = {f2.x, f2.y, f2.z, f2.w, f3.x, f3.y, f3.z, f3.w};
      unsigned int hw[8], lw[8];
#pragma unroll
      for (int q = 0; q < 8; ++q) {
        unsigned ue = __float_as_uint(xe[q]);
        unsigned uo = __float_as_uint(xo[q]);
        hw[q] = (ue >> 16) | (uo & 0xFFFF0000u);
        float el = xe[q] - __uint_as_float(ue & 0xFFFF0000u);
        float ol = xo[q] - __uint_as_float(uo & 0xFFFF0000u);
        lw[q] = (__float_as_uint(el) >> 16) | (__float_as_uint(ol) & 0xFFFF0000u);
        sacc[q] += xe[q] + xo[q];
        ssacc[q] = fmaf(xe[q], xe[q], ssacc[q]);
        ssacc[q] = fmaf(xo[q], xo[q], ssacc[q]);
      }
      *(uint4*)&BH[cb][kp][pb]     = make_uint4(hw[0], hw[1], hw[2], hw[3]);
      *(uint4*)&BH[cb][kp][pb + 4] = make_uint4(hw[4], hw[5], hw[6], hw[7]);
      *(uint4*)&BL[cb][kp][pb]     = make_uint4(lw[0], lw[1], lw[2], lw[3]);
      *(uint4*)&BL[cb][kp][pb + 4] = make_uint4(lw[4], lw[5], lw[6], lw[7]);
    }
    if (t + 1 < 16) {
      const float* pn = vbase + (size_t)((t + 1) * 32 + 2 * kp) * DTT + pb;
      f0 = *(const float4*)(pn);
      f1 = *(const float4*)(pn + 4);
      f2 = *(const float4*)(pn + DTT);
      f3 = *(const float4*)(pn + DTT + 4);
    }
    __syncthreads();
#pragma unroll
    for (int pf = 0; pf < 2; ++pf) {
      int p = pA + pf * 16 + row;
      int kpb = g << 2;
      union { unsigned int u[4]; s16x8 v; } bh, bl;
      bh.u[0] = BH[cb][kpb][p]; bh.u[1] = BH[cb][kpb + 1][p];
      bh.u[2] = BH[cb][kpb + 2][p]; bh.u[3] = BH[cb][kpb + 3][p];
      bl.u[0] = BL[cb][kpb][p]; bl.u[1] = BL[cb][kpb + 1][p];
      bl.u[2] = BL[cb][kpb + 2][p]; bl.u[3] = BL[cb][kpb + 3][p];
#pragma unroll
      for (int a = 0; a < 4; ++a) {
        acc[a][pf] = __builtin_amdgcn_mfma_f32_16x16x32_bf16(AH[a], bh.v, acc[a][pf], 0, 0, 0);
        acc[a][pf] = __builtin_amdgcn_mfma_f32_16x16x32_bf16(AH[a], bl.v, acc[a][pf], 0, 0, 0);
        acc[a][pf] = __builtin_amdgcn_mfma_f32_16x16x32_bf16(AL[a], bh.v, acc[a][pf], 0, 0, 0);
      }
    }
  }

  float (*Sred)[LDB] = (float(*)[LDB])&BH[0][0][0];
  float (*SSred)[LDB] = (float(*)[LDB])&BL[0][0][0];
#pragma unroll
  for (int q = 0; q < 8; ++q) { Sred[kp][pb + q] = sacc[q]; SSred[kp][pb + q] = ssacc[q]; }
  if (tid < 64) SnSum_s[tid] = SnSum[tid];
  __syncthreads();
  if (tid < 128) {
    float s = 0.f, ss = 0.f;
#pragma unroll
    for (int k = 0; k < 16; ++k) { s += Sred[k][tid]; ss += SSred[k][tid]; }
    float mb = s * (1.0f / CC);
    float var = ss - s * mb;
    float nrm = fmaxf(sqrtf(fmaxf(var, 0.f)), EPSV);
    meanv[j * DTT + p0 + tid] = mb;
    normv[j * DTT + p0 + tid] = nrm;
    mb_s[tid] = mb;
    inv_s[tid] = 1.f / nrm;
  }
  __syncthreads();

#pragma unroll
  for (int pf = 0; pf < 2; ++pf) {
    int p = pA + pf * 16 + row;
    float mb = mb_s[p], inv = inv_s[p];
    float mk = mask[p0 + p];
#pragma unroll
    for (int a = 0; a < 4; ++a) {
#pragma unroll
      for (int r = 0; r < 4; ++r) {
        int i = a * 16 + (g << 2) + r;
        float val = (acc[a][pf][r] - mb * SnSum_s[i]) * inv;
        if (mk == 0.f) val = -INFINITY;
        cross[((size_t)i * BB + j) * DTT + p0 + p] = val;
      }
    }
  }
}

// K4: self_score -> pmap out, softmax -> w, wm[b] = sum w*mean
__global__ void k_softmax_w(const float* __restrict__ cross, const float* __restrict__ meanv,
                            float* __restrict__ pmap, float* __restrict__ w, float* __restrict__ wm) {
  int b = blockIdx.x, tid = threadIdx.x;
  __shared__ float red[256];
  const float* row = cross + ((size_t)b * BB + b) * DTT;
  float v[4]; float mx = -INFINITY;
#pragma unroll
  for (int q = 0; q < 4; ++q) {
    v[q] = row[q * 256 + tid];
    pmap[b * DTT + q * 256 + tid] = v[q];
    mx = fmaxf(mx, v[q]);
  }
  mx = bred_max(mx, red, tid, 256);
  float e[4]; float se = 0.f;
#pragma unroll
  for (int q = 0; q < 4; ++q) { e[q] = expf(v[q] - mx); se += e[q]; }
  se = bred_sum(se, red, tid, 256);
  float inv = 1.f / se;
  float wmacc = 0.f;
#pragma unroll
  for (int q = 0; q < 4; ++q) {
    float wv = e[q] * inv;
    w[b * DTT + q * 256 + tid] = wv;
    wmacc += wv * meanv[b * DTT + q * 256 + tid];
  }
  wmacc = bred_sum(wmacc, red, tid, 256);
  if (tid == 0) wm[b] = wmacc;
}

// K5: video_pos[b,c] = sum_p w*videos - wm[b]   (one wave per (b,c); NO atomics)
__global__ void k_vpos(const float* __restrict__ videos, const float* __restrict__ w,
                       const float* __restrict__ wm, float* __restrict__ vp) {
  int wid = (blockIdx.x * 256 + threadIdx.x) >> 6;
  int lane = threadIdx.x & 63;
  int b = wid >> 9, c = wid & 511;
  const float4* vb = (const float4*)(videos + (size_t)(b * CC + c) * DTT) + lane * 4;
  const float4* wb = (const float4*)(w + b * DTT) + lane * 4;
  float acc = 0.f;
#pragma unroll
  for (int q = 0; q < 4; ++q) {
    float4 x = vb[q], y = wb[q];
    acc += x.x * y.x + x.y * y.y + x.z * y.z + x.w * y.w;
  }
#pragma unroll
  for (int off = 32; off > 0; off >>= 1) acc += __shfl_xor(acc, off);
  if (lane == 0) vp[b * CC + c] = acc - wm[b];
}

// Kvpn: ||vp[b]|| and sum_c vp[b,c]  (restored — block-local reduction, no atomics)
__global__ void k_vpnorm(const float* __restrict__ vp, float* __restrict__ vpn,
                         float* __restrict__ vpsum) {
  int b = blockIdx.x, tid = threadIdx.x;
  __shared__ float red[256];
  float x0 = vp[b * CC + tid], x1 = vp[b * CC + tid + 256];
  float ss = bred_sum(x0 * x0 + x1 * x1, red, tid, 256);
  float sm = bred_sum(x0 + x1, red, tid, 256);
  if (tid == 0) { vpn[b] = fmaxf(sqrtf(ss), EPSV); vpsum[b] = sm; }
}

// K6: vsim logits — 16-deep load batching
__global__ void k_vsim_logits(const float* __restrict__ videos, const float* __restrict__ vp,
    const float* __restrict__ vpn, const float* __restrict__ vpsum, const int* __restrict__ nn_idx,
    const float* __restrict__ meanv, const float* __restrict__ normv, float* __restrict__ vslog) {
  int gid = blockIdx.x * 256 + threadIdx.x;
  int b = gid >> 10, p = gid & 1023;
  int nn = nn_idx[b];
  const float* base = videos + (size_t)nn * CC * DTT + p;
  const float* vpr = vp + b * CC;
  float acc = 0.f;
#pragma unroll 1
  for (int c0 = 0; c0 < CC; c0 += 16) {
    float v[16];
#pragma unroll
    for (int u = 0; u < 16; ++u) v[u] = base[(size_t)(c0 + u) * DTT];
#pragma unroll
    for (int u = 0; u < 16; ++u) acc = fmaf(vpr[c0 + u], v[u], acc);
  }
  acc -= meanv[nn * DTT + p] * vpsum[b];
  vslog[gid] = acc / (vpn[b] * normv[nn * DTT + p]);
}

// K7: softmax(vslog) in-place -> vsim ; svp, svn
__global__ void k_softmax_vsim(float* __restrict__ vslog, const int* __restrict__ nn_idx,
    const float* __restrict__ meanv, const float* __restrict__ mask,
    float* __restrict__ svp, float* __restrict__ svn) {
  int b = blockIdx.x, tid = threadIdx.x;
  __shared__ float red[256];
  int nn = nn_idx[b];
  float v[4]; float mx = -INFINITY;
#pragma unroll
  for (int q = 0; q < 4; ++q) { v[q] = vslog[b * DTT + q * 256 + tid]; mx = fmaxf(mx, v[q]); }
  mx = bred_max(mx, red, tid, 256);
  float e[4]; float se = 0.f;
#pragma unroll
  for (int q = 0; q < 4; ++q) { e[q] = expf(v[q] - mx); se += e[q]; }
  se = bred_sum(se, red, tid, 256);
  float inv = 1.f / se;
  float sp = 0.f, sn2 = 0.f;
#pragma unroll
  for (int q = 0; q < 4; ++q) {
    int p = q * 256 + tid;
    float vs = e[q] * inv;
    vslog[b * DTT + p] = vs;
    float mm = meanv[nn * DTT + p];
    sp += vs * mm;
    sn2 += (1.f - vs) * mask[p] * mm;
  }
  sp = bred_sum(sp, red, tid, 256);
  sn2 = bred_sum(sn2, red, tid, 256);
  if (tid == 0) { svp[b] = sp; svn[b] = sn2; }
}

// K8: p_v and n_v  (one wave per (b,c))
__global__ void k_pvnv(const float* __restrict__ videos, const float* __restrict__ vsim,
    const int* __restrict__ nn_idx, const float* __restrict__ mask,
    const float* __restrict__ svp, const float* __restrict__ svn, const int* __restrict__ vn_p,
    float* __restrict__ pv, float* __restrict__ nv) {
  int wid = (blockIdx.x * 256 + threadIdx.x) >> 6;
  int lane = threadIdx.x & 63;
  int b = wid >> 9, c = wid & 511;
  int nn = nn_idx[b];
  const float4* vb = (const float4*)(videos + (size_t)(nn * CC + c) * DTT) + lane * 4;
  const float4* vs4 = (const float4*)(vsim + b * DTT) + lane * 4;
  const float4* m4 = ((const float4*)mask) + lane * 4;
  float ap = 0.f, an = 0.f;
#pragma unroll
  for (int q = 0; q < 4; ++q) {
    float4 x = vb[q], s = vs4[q], m = m4[q];
    ap += x.x * s.x + x.y * s.y + x.z * s.z + x.w * s.w;
    an += x.x * (1.f - s.x) * m.x + x.y * (1.f - s.y) * m.y + x.z * (1.f - s.z) * m.z + x.w * (1.f - s.w) * m.w;
  }
#pragma unroll
  for (int off = 32; off > 0; off >>= 1) { ap += __shfl_xor(ap, off); an += __shfl_xor(an, off); }
  if (lane == 0) {
    float kd = (float)(*vn_p - 1);
    pv[b * CC + c] = ap - svp[b];
    nv[b * CC + c] = (an - svn[b]) / kd;
  }
}

// Kvas+Kcrov fused: vas phase (coalesced SnT gathers) then crov phase.
__global__ void k_vascrov(const float* __restrict__ vp, const float* __restrict__ vpn,
                          const float* __restrict__ SnT, const int* __restrict__ negidx,
                          const float* __restrict__ pv, const float* __restrict__ nv,
                          const float* __restrict__ nnsim,
                          float* __restrict__ vasrow, float* __restrict__ crovrow) {
  int i = blockIdx.x, tid = threadIdx.x;  // 256
  int t = tid & 63, cq = tid >> 6;
  __shared__ float part[4][68];
  __shared__ float redv[64];
  __shared__ float red[256];
  float invn = 1.f / vpn[i];
  // --- vas phase ---
  {
    int nj = (t < NNEG) ? negidx[i * NNEG + t] : i;  // t==63 row computes pos
    float acc = 0.f;
    const float* vpr = vp + i * CC + cq * 128;
    const float* st = SnT + (size_t)(cq * 128) * BB + nj;
#pragma unroll 8
    for (int c = 0; c < 128; ++c) acc = fmaf(vpr[c], st[(size_t)c * BB], acc);
    part[cq][t] = acc;
    __syncthreads();
    if (tid < 64) redv[tid] = part[0][tid] + part[1][tid] + part[2][tid] + part[3][tid];
    __syncthreads();
    float pos = redv[63] * invn;
    float contrib = (tid < NNEG) ? fmaxf(MARGIN_ + redv[tid] * invn - pos, 0.f) : 0.f;
    float s = bred_sum(contrib, red, tid, 256);
    if (tid == 0) vasrow[i] = s / (float)NNEG;
  }
  // --- crov phase ---
  {
    float dp = 0.f, pp = 0.f, dn = 0.f, nn2 = 0.f;
    for (int c = tid; c < CC; c += 256) {
      float a = vp[i * CC + c], x = pv[i * CC + c], y = nv[i * CC + c];
      dp += a * x; pp += x * x; dn += a * y; nn2 += y * y;
    }
    dp = bred_sum(dp, red, tid, 256);
    pp = bred_sum(pp, red, tid, 256);
    dn = bred_sum(dn, red, tid, 256);
    nn2 = bred_sum(nn2, red, tid, 256);
    if (tid == 0) {
      float cosp = dp * invn / fmaxf(sqrtf(pp), EPSV);
      float cosn = dn * invn / fmaxf(sqrtf(nn2), EPSV);
      float crov = fmaxf(MARGIN_ + cosn - cosp, 0.f);
      crovrow[i] = (nnsim[i] > 0.9f) ? crov : 0.f;
    }
  }
}

// K9 fused: block per (i,j). Wave 0: radix select + rank-order into LDS (ti, tv).
// Then all 4 waves: decay products (shuffle version) + wave-0 softmax score.
__global__ __launch_bounds__(256) void k_seldecay(const float* __restrict__ cross,
    const __half* __restrict__ L16, const float* __restrict__ lam_p,
    const int* __restrict__ vn_p, float* __restrict__ scores) {
  __shared__ unsigned int hist[256];
  __shared__ unsigned int sel[128];
  __shared__ unsigned int selk[128];
  __shared__ unsigned int cnt;
  __shared__ unsigned ti[128];
  __shared__ float tv[128];
  __shared__ float dks[128];
  int ij = blockIdx.x, tid = threadIdx.x;
  int wv = tid >> 6, lane = tid & 63;
  int K = *vn_p; if (K > 128) K = 128;
  float lam = *lam_p;

  if (wv == 0) {
    const float* row = cross + (size_t)ij * DTT;
    unsigned int v[16];
#pragma unroll
    for (int q = 0; q < 16; ++q) {
      unsigned u = __float_as_uint(row[q * 64 + lane]);
      v[q] = (u & 0x80000000u) ? ~u : (u | 0x80000000u);
    }
    if (lane == 0) cnt = 0u;
    __builtin_amdgcn_wave_barrier();

    unsigned prefix = 0u, pmask = 0u;
    int remaining = K;
    for (int shift = 24; shift >= 0; shift -= 8) {
#pragma unroll
      for (int q = 0; q < 4; ++q) hist[lane * 4 + q] = 0u;
      __builtin_amdgcn_wave_barrier();
#pragma unroll
      for (int q = 0; q < 16; ++q) {
        if ((v[q] & pmask) == prefix)
          atomicAdd(&hist[(v[q] >> shift) & 255u], 1u);
      }
      __builtin_amdgcn_wave_barrier();
      unsigned c0 = hist[lane * 4], c1 = hist[lane * 4 + 1];
      unsigned c2 = hist[lane * 4 + 2], c3 = hist[lane * 4 + 3];
      unsigned s = c0 + c1 + c2 + c3;
      unsigned inc = s;
#pragma unroll
      for (int off = 1; off < 64; off <<= 1) {
        unsigned t = __shfl_down(inc, off);
        if (lane + off < 64) inc += t;
      }
      unsigned exc = inc - s;
      bool found = (exc < (unsigned)remaining) && (inc >= (unsigned)remaining);
      unsigned long long bmask = __ballot(found);
      int winner = (int)(__ffsll((unsigned long long)bmask) - 1);
      unsigned packed = 0u;
      if (found) {
        unsigned c = exc;
        unsigned cc[4] = {c0, c1, c2, c3};
        int d = lane * 4;
#pragma unroll
        for (int q = 3; q >= 0; --q) {
          if (c + cc[q] >= (unsigned)remaining) { d = lane * 4 + q; break; }
          c += cc[q];
        }
        packed = ((unsigned)d << 16) | (unsigned)(remaining - (int)c);
      }
      packed = __shfl(packed, winner);
      prefix |= (packed >> 16) << shift;
      remaining = (int)(packed & 0xFFFFu);
      pmask |= 255u << shift;
    }

#pragma unroll
    for (int q = 0; q < 16; ++q) {
      if (v[q] > prefix) {
        unsigned pos = atomicAdd(&cnt, 1u);
        sel[pos] = (unsigned)(q * 64 + lane);
        selk[pos] = v[q];
      }
    }
    __builtin_amdgcn_wave_barrier();
    {
      int base = K - remaining;
      int last = -1;
      for (int t = 0; t < remaining; ++t) {
        int mymin = 0x7FFFFFFF;
#pragma unroll
        for (int q = 0; q < 16; ++q) {
          int idx = q * 64 + lane;
          if (v[q] == prefix && idx > last && idx < mymin) mymin = idx;
        }
#pragma unroll
        for (int off = 32; off > 0; off >>= 1) mymin = min(mymin, __shfl_xor(mymin, off));
        if (lane == 0) { sel[base + t] = (unsigned)mymin; selk[base + t] = prefix; }
        last = mymin;
      }
    }
    __builtin_amdgcn_wave_barrier();

    for (int e = lane; e < K; e += 64) {
      unsigned myidx = sel[e], myk = selk[e];
      int rank = 0;
      for (int m = 0; m < K; ++m) {
        unsigned ok = selk[m];
        rank += (ok > myk || (ok == myk && sel[m] < myidx)) ? 1 : 0;
      }
      unsigned u = (myk & 0x80000000u) ? (myk & 0x7FFFFFFFu) : ~myk;
      ti[rank] = myidx;
      tv[rank] = __uint_as_float(u);
    }
  }
  __syncthreads();

  for (int r = wv; r < K; r += 4) {
    const __half* irow = L16 + (size_t)ti[r] * DTT;
    float f = 1.f;
    if (lane < r && lane < 64) f = __half2float(irow[ti[lane]]);
    float prod = f;
#pragma unroll
    for (int off = 32; off > 0; off >>= 1) prod *= __shfl_xor(prod, off);
    if (r > 64 && prod > 1e-14f) {
      float f2 = 1.f;
      int m = 64 + lane;
      if (m < r) f2 = __half2float(irow[ti[m]]);
#pragma unroll
      for (int off = 32; off > 0; off >>= 1) f2 *= __shfl_xor(f2, off);
      prod *= f2;
    }
    if (lane == 0) dks[r] = prod;
  }
  __syncthreads();

  if (wv == 0) {
    bool okA = (lane < K), okB = (lane + 64 < K);
    float vA = okA ? tv[lane] : 0.f;
    float vB = okB ? tv[lane + 64] : 0.f;
    float mx = fmaxf(okA ? lam * vA : -INFINITY, okB ? lam * vB : -INFINITY);
#pragma unroll
    for (int off = 32; off > 0; off >>= 1) mx = fmaxf(mx, __shfl_xor(mx, off));
    float eA = okA ? expf(lam * vA - mx) : 0.f;
    float eB = okB ? expf(lam * vB - mx) : 0.f;
    float se = eA + eB;
    float sc = (okA ? eA * dks[lane] * vA : 0.f) + (okB ? eB * dks[lane + 64] * vB : 0.f);
#pragma unroll
    for (int off = 32; off > 0; off >>= 1) {
      se += __shfl_xor(se, off);
      sc += __shfl_xor(sc, off);
    }
    if (lane == 0) scores[ij] = sc / se;
  }
}

// Kfinal: hinge maxima + loss
__global__ void k_final(const float* __restrict__ scores, const float* __restrict__ vasrow,
                        const float* __restrict__ crovrow, float* __restrict__ out) {
  int tid = threadIdx.x;  // 64 threads
  __shared__ float sm[BB * BB];
  __shared__ float red[64];
  for (int q = tid; q < BB * BB; q += 64) sm[q] = scores[q];
  __syncthreads();
  float di = sm[tid * BB + tid];
  float rowmax = 0.f, colmax = 0.f;
  for (int k = 0; k < BB; ++k) {
    if (k != tid) {
      rowmax = fmaxf(rowmax, fmaxf(MARGIN_ + sm[tid * BB + k] - di, 0.f));
      colmax = fmaxf(colmax, fmaxf(MARGIN_ + sm[k * BB + tid] - di, 0.f));
    }
  }
  float total = bred_sum(rowmax + colmax + vasrow[tid] + crovrow[tid], red, tid, 64);
  if (tid == 0) out[0] = total * (1.0f / BB);
}

extern "C" void kernel_launch(void* const* d_in, const int* in_sizes, int n_in,
                              void* d_out, int out_size, void* d_ws, size_t ws_size,
                              hipStream_t stream) {
  const float* videos = (const float*)d_in[0];
  const float* sentences = (const float*)d_in[1];
  const float* lam = (const float*)d_in[2];
  const float* mask = (const float*)d_in[3];
  const int* valid_num = (const int*)d_in[4];
  const float* iou_maps = (const float*)d_in[5];
  float* out = (float*)d_out;
  float* pmap = out + 1;

  float* ws = (float*)d_ws;
  float* Sn = ws;                      // 32768
  float* SnT = Sn + 32768;             // 32768
  float* SnSum = SnT + 32768;          // 64
  float* meanv = SnSum + 64;           // 65536
  float* normv = meanv + 65536;        // 65536
  float* cross = normv + 65536;        // 4194304
  float* w = cross + 4194304;          // 65536
  float* wm = w + 65536;               // 64
  float* vp = wm + 64;                 // 32768
  float* vpn = vp + 32768;             // 64
  float* vpsum = vpn + 64;             // 64
  float* nnsim = vpsum + 64;           // 64
  float* vslog = nnsim + 64;           // 65536 (becomes vsim in-place)
  float* svp = vslog + 65536;          // 64
  float* svn = svp + 64;               // 64
  float* pvb = svn + 64;               // 32768
  float* nvb = pvb + 32768;            // 32768
  float* vasrow = nvb + 32768;         // 64
  float* crovrow = vasrow + 64;        // 64
  float* scores = crovrow + 64;        // 4096
  int* nn_idx = (int*)(scores + 4096); // 64
  int* negidx = nn_idx + 64;           // 3392
  unsigned* ordi_unused = (unsigned*)(negidx + 3392);  // 524288 (slot kept)
  float* ordv_unused = (float*)(ordi_unused + 524288); // 524288 (slot kept)
  __half* L16 = (__half*)(ordv_unused + 524288);       // 1048576 halfs = 2MB
  unsigned short* SnH16 = (unsigned short*)(L16 + 1048576);  // 32768 u16
  unsigned short* SnL16 = SnH16 + 32768;                     // 32768 u16

  k_sentprep<<<1088, 256, 0, stream>>>(sentences, iou_maps, Sn, SnT, SnH16, SnL16, SnSum, L16);
  k_sim<<<64, 256, 0, stream>>>(Sn, SnT, nn_idx, negidx, nnsim);
  k_cross<<<512, 256, 0, stream>>>(videos, SnH16, SnL16, SnSum, mask, cross, meanv, normv);
  k_softmax_w<<<64, 256, 0, stream>>>(cross, meanv, pmap, w, wm);
  k_vpos<<<8192, 256, 0, stream>>>(videos, w, wm, vp);
  k_vpnorm<<<64, 256, 0, stream>>>(vp, vpn, vpsum);
  k_vsim_logits<<<256, 256, 0, stream>>>(videos, vp, vpn, vpsum, nn_idx, meanv, normv, vslog);
  k_softmax_vsim<<<64, 256, 0, stream>>>(vslog, nn_idx, meanv, mask, svp, svn);
  k_pvnv<<<8192, 256, 0, stream>>>(videos, vslog, nn_idx, mask, svp, svn, valid_num, pvb, nvb);
  k_vascrov<<<64, 256, 0, stream>>>(vp, vpn, SnT, negidx, pvb, nvb, nnsim, vasrow, crovrow);
  k_seldecay<<<4096, 256, 0, stream>>>(cross, L16, lam, valid_num, scores);
  k_final<<<1, 64, 0, stream>>>(scores, vasrow, crovrow, out);
}

// Round 11
// 414.229 us; speedup vs baseline: 1.6196x; 1.0096x over previous
//
#include <hip/hip_runtime.h>
#include <hip/hip_fp16.h>
#include <math.h>

#define BB 64
#define CC 512
#define DTT 1024
#define NNEG 53
#define MARGIN_ 0.2f
#define EPSV 1e-8f
#define LDB 132

typedef short s16x8 __attribute__((ext_vector_type(8)));
typedef float f32x4 __attribute__((ext_vector_type(4)));

__device__ __forceinline__ float bred_sum(float v, float* red, int tid, int nt) {
  red[tid] = v; __syncthreads();
  for (int s = nt >> 1; s > 0; s >>= 1) { if (tid < s) red[tid] += red[tid + s]; __syncthreads(); }
  float r = red[0]; __syncthreads();
  return r;
}
__device__ __forceinline__ float bred_max(float v, float* red, int tid, int nt) {
  red[tid] = v; __syncthreads();
  for (int s = nt >> 1; s > 0; s >>= 1) { if (tid < s) red[tid] = fmaxf(red[tid], red[tid + s]); __syncthreads(); }
  float r = red[0]; __syncthreads();
  return r;
}

// K1+Kprep fused: blocks 0..63 = sentence prep; blocks 64..1087 = iou->fp16 prep.
__global__ void k_sentprep(const float* __restrict__ sent, const float* __restrict__ iou,
                           float* __restrict__ Sn, float* __restrict__ SnT,
                           unsigned short* __restrict__ SnH, unsigned short* __restrict__ SnL,
                           float* __restrict__ SnSum, __half* __restrict__ L16) {
  int tid = threadIdx.x;
  if (blockIdx.x >= 64) {
    int g = ((blockIdx.x - 64) * 256 + tid) * 4;
    float4 x = *(const float4*)(iou + g);
    __half2 h0 = __floats2half2_rn(1.f - x.x, 1.f - x.y);
    __half2 h1 = __floats2half2_rn(1.f - x.z, 1.f - x.w);
    *(__half2*)(L16 + g) = h0;
    *(__half2*)(L16 + g + 2) = h1;
    return;
  }
  int b = blockIdx.x;
  __shared__ float red[256];
  float x0 = sent[b * CC + tid], x1 = sent[b * CC + tid + 256];
  float mean = bred_sum(x0 + x1, red, tid, 256) * (1.0f / CC);
  float s0 = x0 - mean, s1 = x1 - mean;
  float ss = bred_sum(s0 * s0 + s1 * s1, red, tid, 256);
  float nrm = fmaxf(sqrtf(ss), EPSV);
  float n0 = s0 / nrm, n1 = s1 / nrm;
  Sn[b * CC + tid] = n0; Sn[b * CC + tid + 256] = n1;
  SnT[tid * BB + b] = n0; SnT[(tid + 256) * BB + b] = n1;
  unsigned u0 = __float_as_uint(n0), u1 = __float_as_uint(n1);
  SnH[b * CC + tid] = (unsigned short)(u0 >> 16);
  SnH[b * CC + tid + 256] = (unsigned short)(u1 >> 16);
  float l0 = n0 - __uint_as_float(u0 & 0xFFFF0000u);
  float l1 = n1 - __uint_as_float(u1 & 0xFFFF0000u);
  SnL[b * CC + tid] = (unsigned short)(__float_as_uint(l0) >> 16);
  SnL[b * CC + tid + 256] = (unsigned short)(__float_as_uint(l1) >> 16);
  float sn = bred_sum(n0 + n1, red, tid, 256);
  if (tid == 0) SnSum[b] = sn;
}

// KS: sim row i; 256 threads = (j, c-quarter); coalesced via SnT; rank logic on 64.
__global__ void k_sim(const float* __restrict__ Sn, const float* __restrict__ SnT,
                      int* __restrict__ nn_idx, int* __restrict__ negidx,
                      float* __restrict__ nnsim) {
  int i = blockIdx.x, tid = threadIdx.x;
  int j = tid & 63, cq = tid >> 6;
  __shared__ float part[4][68];
  __shared__ float srow[BB];
  float acc = 0.f;
  const float* si = Sn + i * CC + cq * 128;
  const float* st = SnT + (size_t)(cq * 128) * BB + j;
#pragma unroll 8
  for (int c = 0; c < 128; ++c) acc = fmaf(si[c], st[(size_t)c * BB], acc);
  part[cq][j] = acc;
  __syncthreads();
  if (tid < 64) srow[tid] = part[0][tid] + part[1][tid] + part[2][tid] + part[3][tid];
  __syncthreads();
  if (tid < 64) {
    float mv = srow[tid];
    int rank = 0;
    for (int k = 0; k < BB; ++k) {
      float vk = srow[k];
      if (vk > mv || (vk == mv && k < tid)) rank++;
    }
    if (rank == 1) { nn_idx[i] = tid; nnsim[i] = mv; }
    if (rank >= 6 && rank < 59) negidx[i * NNEG + rank - 6] = tid;
  }
}

// K3: split-bf16 MFMA GEMM, double-buffered LDS (measured-best, unchanged).
__global__ __launch_bounds__(256) void k_cross(const float* __restrict__ videos,
    const unsigned short* __restrict__ SnH, const unsigned short* __restrict__ SnL,
    const float* __restrict__ SnSum, const float* __restrict__ mask,
    float* __restrict__ cross, float* __restrict__ meanv, float* __restrict__ normv) {
  __shared__ unsigned int BH[2][16][LDB];
  __shared__ unsigned int BL[2][16][LDB];
  __shared__ float SnSum_s[64];
  __shared__ float mb_s[128];
  __shared__ float inv_s[128];

  int tid = threadIdx.x;
  int j = blockIdx.x >> 3;
  int p0 = (blockIdx.x & 7) << 7;
  int lane = tid & 63;
  int wv = tid >> 6;
  int row = lane & 15;
  int g = lane >> 4;
  int g8 = g << 3;
  int pA = wv << 5;

  int kp = tid >> 4;
  int pb = (tid & 15) << 3;

  const float* vbase = videos + ((size_t)j * CC) * DTT + p0;

  f32x4 acc[4][2];
#pragma unroll
  for (int a = 0; a < 4; ++a)
#pragma unroll
    for (int pf = 0; pf < 2; ++pf)
#pragma unroll
      for (int r = 0; r < 4; ++r) acc[a][pf][r] = 0.f;

  float sacc[8], ssacc[8];
#pragma unroll
  for (int q = 0; q < 8; ++q) { sacc[q] = 0.f; ssacc[q] = 0.f; }

  const float* pr = vbase + (size_t)(2 * kp) * DTT + pb;
  float4 f0 = *(const float4*)(pr);
  float4 f1 = *(const float4*)(pr + 4);
  float4 f2 = *(const float4*)(pr + DTT);
  float4 f3 = *(const float4*)(pr + DTT + 4);

#pragma unroll
  for (int t = 0; t < 16; ++t) {
    int kc = t * 32;
    int cb = t & 1;
    s16x8 AH[4], AL[4];
#pragma unroll
    for (int a = 0; a < 4; ++a) {
      int off = (a * 16 + row) * CC + kc + g8;
      AH[a] = *(const s16x8*)(SnH + off);
      AL[a] = *(const s16x8*)(SnL + off);
    }
    {
      float xe[8] = {f0.x, f0.y, f0.z, f0.w, f1.x, f1.y, f1.z, f1.w};
      float xo[8] = {f2.x, f2.y, f2.z, f2.w, f3.x, f3.y, f3.z, f3.w};
      unsigned int hw[8], lw[8];
#pragma unroll
      for (int q = 0; q < 8; ++q) {
        unsigned ue = __float_as_uint(xe[q]);
        unsigned uo = __float_as_uint(xo[q]);
        hw[q] = (ue >> 16) | (uo & 0xFFFF0000u);
        float el = xe[q] - __uint_as_float(ue & 0xFFFF0000u);
        float ol = xo[q] - __uint_as_float(uo & 0xFFFF0000u);
        lw[q] = (__float_as_uint(el) >> 16) | (__float_as_uint(ol) & 0xFFFF0000u);
        sacc[q] += xe[q] + xo[q];
        ssacc[q] = fmaf(xe[q], xe[q], ssacc[q]);
        ssacc[q] = fmaf(xo[q], xo[q], ssacc[q]);
      }
      *(uint4*)&BH[cb][kp][pb]     = make_uint4(hw[0], hw[1], hw[2], hw[3]);
      *(uint4*)&BH[cb][kp][pb + 4] = make_uint4(hw[4], hw[5], hw[6], hw[7]);
      *(uint4*)&BL[cb][kp][pb]     = make_uint4(lw[0], lw[1], lw[2], lw[3]);
      *(uint4*)&BL[cb][kp][pb + 4] = make_uint4(lw[4], lw[5], lw[6], lw[7]);
    }
    if (t + 1 < 16) {
      const float* pn = vbase + (size_t)((t + 1) * 32 + 2 * kp) * DTT + pb;
      f0 = *(const float4*)(pn);
      f1 = *(const float4*)(pn + 4);
      f2 = *(const float4*)(pn + DTT);
      f3 = *(const float4*)(pn + DTT + 4);
    }
    __syncthreads();
#pragma unroll
    for (int pf = 0; pf < 2; ++pf) {
      int p = pA + pf * 16 + row;
      int kpb = g << 2;
      union { unsigned int u[4]; s16x8 v; } bh, bl;
      bh.u[0] = BH[cb][kpb][p]; bh.u[1] = BH[cb][kpb + 1][p];
      bh.u[2] = BH[cb][kpb + 2][p]; bh.u[3] = BH[cb][kpb + 3][p];
      bl.u[0] = BL[cb][kpb][p]; bl.u[1] = BL[cb][kpb + 1][p];
      bl.u[2] = BL[cb][kpb + 2][p]; bl.u[3] = BL[cb][kpb + 3][p];
#pragma unroll
      for (int a = 0; a < 4; ++a) {
        acc[a][pf] = __builtin_amdgcn_mfma_f32_16x16x32_bf16(AH[a], bh.v, acc[a][pf], 0, 0, 0);
        acc[a][pf] = __builtin_amdgcn_mfma_f32_16x16x32_bf16(AH[a], bl.v, acc[a][pf], 0, 0, 0);
        acc[a][pf] = __builtin_amdgcn_mfma_f32_16x16x32_bf16(AL[a], bh.v, acc[a][pf], 0, 0, 0);
      }
    }
  }

  float (*Sred)[LDB] = (float(*)[LDB])&BH[0][0][0];
  float (*SSred)[LDB] = (float(*)[LDB])&BL[0][0][0];
#pragma unroll
  for (int q = 0; q < 8; ++q) { Sred[kp][pb + q] = sacc[q]; SSred[kp][pb + q] = ssacc[q]; }
  if (tid < 64) SnSum_s[tid] = SnSum[tid];
  __syncthreads();
  if (tid < 128) {
    float s = 0.f, ss = 0.f;
#pragma unroll
    for (int k = 0; k < 16; ++k) { s += Sred[k][tid]; ss += SSred[k][tid]; }
    float mb = s * (1.0f / CC);
    float var = ss - s * mb;
    float nrm = fmaxf(sqrtf(fmaxf(var, 0.f)), EPSV);
    meanv[j * DTT + p0 + tid] = mb;
    normv[j * DTT + p0 + tid] = nrm;
    mb_s[tid] = mb;
    inv_s[tid] = 1.f / nrm;
  }
  __syncthreads();

#pragma unroll
  for (int pf = 0; pf < 2; ++pf) {
    int p = pA + pf * 16 + row;
    float mb = mb_s[p], inv = inv_s[p];
    float mk = mask[p0 + p];
#pragma unroll
    for (int a = 0; a < 4; ++a) {
#pragma unroll
      for (int r = 0; r < 4; ++r) {
        int i = a * 16 + (g << 2) + r;
        float val = (acc[a][pf][r] - mb * SnSum_s[i]) * inv;
        if (mk == 0.f) val = -INFINITY;
        cross[((size_t)i * BB + j) * DTT + p0 + p] = val;
      }
    }
  }
}

// K4: self_score -> pmap out, softmax -> w, wm[b] = sum w*mean
__global__ void k_softmax_w(const float* __restrict__ cross, const float* __restrict__ meanv,
                            float* __restrict__ pmap, float* __restrict__ w, float* __restrict__ wm) {
  int b = blockIdx.x, tid = threadIdx.x;
  __shared__ float red[256];
  const float* row = cross + ((size_t)b * BB + b) * DTT;
  float v[4]; float mx = -INFINITY;
#pragma unroll
  for (int q = 0; q < 4; ++q) {
    v[q] = row[q * 256 + tid];
    pmap[b * DTT + q * 256 + tid] = v[q];
    mx = fmaxf(mx, v[q]);
  }
  mx = bred_max(mx, red, tid, 256);
  float e[4]; float se = 0.f;
#pragma unroll
  for (int q = 0; q < 4; ++q) { e[q] = expf(v[q] - mx); se += e[q]; }
  se = bred_sum(se, red, tid, 256);
  float inv = 1.f / se;
  float wmacc = 0.f;
#pragma unroll
  for (int q = 0; q < 4; ++q) {
    float wv = e[q] * inv;
    w[b * DTT + q * 256 + tid] = wv;
    wmacc += wv * meanv[b * DTT + q * 256 + tid];
  }
  wmacc = bred_sum(wmacc, red, tid, 256);
  if (tid == 0) wm[b] = wmacc;
}

// K5: video_pos[b,c] = sum_p w*videos - wm[b]   (one wave per (b,c); NO atomics)
__global__ void k_vpos(const float* __restrict__ videos, const float* __restrict__ w,
                       const float* __restrict__ wm, float* __restrict__ vp) {
  int wid = (blockIdx.x * 256 + threadIdx.x) >> 6;
  int lane = threadIdx.x & 63;
  int b = wid >> 9, c = wid & 511;
  const float4* vb = (const float4*)(videos + (size_t)(b * CC + c) * DTT) + lane * 4;
  const float4* wb = (const float4*)(w + b * DTT) + lane * 4;
  float acc = 0.f;
#pragma unroll
  for (int q = 0; q < 4; ++q) {
    float4 x = vb[q], y = wb[q];
    acc += x.x * y.x + x.y * y.y + x.z * y.z + x.w * y.w;
  }
#pragma unroll
  for (int off = 32; off > 0; off >>= 1) acc += __shfl_xor(acc, off);
  if (lane == 0) vp[b * CC + c] = acc - wm[b];
}

// Kvpn: ||vp[b]|| and sum_c vp[b,c]
__global__ void k_vpnorm(const float* __restrict__ vp, float* __restrict__ vpn,
                         float* __restrict__ vpsum) {
  int b = blockIdx.x, tid = threadIdx.x;
  __shared__ float red[256];
  float x0 = vp[b * CC + tid], x1 = vp[b * CC + tid + 256];
  float ss = bred_sum(x0 * x0 + x1 * x1, red, tid, 256);
  float sm = bred_sum(x0 + x1, red, tid, 256);
  if (tid == 0) { vpn[b] = fmaxf(sqrtf(ss), EPSV); vpsum[b] = sm; }
}

// K6: vsim logits — 16-deep load batching
__global__ void k_vsim_logits(const float* __restrict__ videos, const float* __restrict__ vp,
    const float* __restrict__ vpn, const float* __restrict__ vpsum, const int* __restrict__ nn_idx,
    const float* __restrict__ meanv, const float* __restrict__ normv, float* __restrict__ vslog) {
  int gid = blockIdx.x * 256 + threadIdx.x;
  int b = gid >> 10, p = gid & 1023;
  int nn = nn_idx[b];
  const float* base = videos + (size_t)nn * CC * DTT + p;
  const float* vpr = vp + b * CC;
  float acc = 0.f;
#pragma unroll 1
  for (int c0 = 0; c0 < CC; c0 += 16) {
    float v[16];
#pragma unroll
    for (int u = 0; u < 16; ++u) v[u] = base[(size_t)(c0 + u) * DTT];
#pragma unroll
    for (int u = 0; u < 16; ++u) acc = fmaf(vpr[c0 + u], v[u], acc);
  }
  acc -= meanv[nn * DTT + p] * vpsum[b];
  vslog[gid] = acc / (vpn[b] * normv[nn * DTT + p]);
}

// K7: softmax(vslog) in-place -> vsim ; svp, svn
__global__ void k_softmax_vsim(float* __restrict__ vslog, const int* __restrict__ nn_idx,
    const float* __restrict__ meanv, const float* __restrict__ mask,
    float* __restrict__ svp, float* __restrict__ svn) {
  int b = blockIdx.x, tid = threadIdx.x;
  __shared__ float red[256];
  int nn = nn_idx[b];
  float v[4]; float mx = -INFINITY;
#pragma unroll
  for (int q = 0; q < 4; ++q) { v[q] = vslog[b * DTT + q * 256 + tid]; mx = fmaxf(mx, v[q]); }
  mx = bred_max(mx, red, tid, 256);
  float e[4]; float se = 0.f;
#pragma unroll
  for (int q = 0; q < 4; ++q) { e[q] = expf(v[q] - mx); se += e[q]; }
  se = bred_sum(se, red, tid, 256);
  float inv = 1.f / se;
  float sp = 0.f, sn2 = 0.f;
#pragma unroll
  for (int q = 0; q < 4; ++q) {
    int p = q * 256 + tid;
    float vs = e[q] * inv;
    vslog[b * DTT + p] = vs;
    float mm = meanv[nn * DTT + p];
    sp += vs * mm;
    sn2 += (1.f - vs) * mask[p] * mm;
  }
  sp = bred_sum(sp, red, tid, 256);
  sn2 = bred_sum(sn2, red, tid, 256);
  if (tid == 0) { svp[b] = sp; svn[b] = sn2; }
}

// K8: p_v and n_v  (one wave per (b,c))
__global__ void k_pvnv(const float* __restrict__ videos, const float* __restrict__ vsim,
    const int* __restrict__ nn_idx, const float* __restrict__ mask,
    const float* __restrict__ svp, const float* __restrict__ svn, const int* __restrict__ vn_p,
    float* __restrict__ pv, float* __restrict__ nv) {
  int wid = (blockIdx.x * 256 + threadIdx.x) >> 6;
  int lane = threadIdx.x & 63;
  int b = wid >> 9, c = wid & 511;
  int nn = nn_idx[b];
  const float4* vb = (const float4*)(videos + (size_t)(nn * CC + c) * DTT) + lane * 4;
  const float4* vs4 = (const float4*)(vsim + b * DTT) + lane * 4;
  const float4* m4 = ((const float4*)mask) + lane * 4;
  float ap = 0.f, an = 0.f;
#pragma unroll
  for (int q = 0; q < 4; ++q) {
    float4 x = vb[q], s = vs4[q], m = m4[q];
    ap += x.x * s.x + x.y * s.y + x.z * s.z + x.w * s.w;
    an += x.x * (1.f - s.x) * m.x + x.y * (1.f - s.y) * m.y + x.z * (1.f - s.z) * m.z + x.w * (1.f - s.w) * m.w;
  }
#pragma unroll
  for (int off = 32; off > 0; off >>= 1) { ap += __shfl_xor(ap, off); an += __shfl_xor(an, off); }
  if (lane == 0) {
    float kd = (float)(*vn_p - 1);
    pv[b * CC + c] = ap - svp[b];
    nv[b * CC + c] = (an - svn[b]) / kd;
  }
}

// Kvas+Kcrov fused: vas phase (coalesced SnT gathers) then crov phase.
__global__ void k_vascrov(const float* __restrict__ vp, const float* __restrict__ vpn,
                          const float* __restrict__ SnT, const int* __restrict__ negidx,
                          const float* __restrict__ pv, const float* __restrict__ nv,
                          const float* __restrict__ nnsim,
                          float* __restrict__ vasrow, float* __restrict__ crovrow) {
  int i = blockIdx.x, tid = threadIdx.x;  // 256
  int t = tid & 63, cq = tid >> 6;
  __shared__ float part[4][68];
  __shared__ float redv[64];
  __shared__ float red[256];
  float invn = 1.f / vpn[i];
  // --- vas phase ---
  {
    int nj = (t < NNEG) ? negidx[i * NNEG + t] : i;  // t==63 row computes pos
    float acc = 0.f;
    const float* vpr = vp + i * CC + cq * 128;
    const float* st = SnT + (size_t)(cq * 128) * BB + nj;
#pragma unroll 8
    for (int c = 0; c < 128; ++c) acc = fmaf(vpr[c], st[(size_t)c * BB], acc);
    part[cq][t] = acc;
    __syncthreads();
    if (tid < 64) redv[tid] = part[0][tid] + part[1][tid] + part[2][tid] + part[3][tid];
    __syncthreads();
    float pos = redv[63] * invn;
    float contrib = (tid < NNEG) ? fmaxf(MARGIN_ + redv[tid] * invn - pos, 0.f) : 0.f;
    float s = bred_sum(contrib, red, tid, 256);
    if (tid == 0) vasrow[i] = s / (float)NNEG;
  }
  // --- crov phase ---
  {
    float dp = 0.f, pp = 0.f, dn = 0.f, nn2 = 0.f;
    for (int c = tid; c < CC; c += 256) {
      float a = vp[i * CC + c], x = pv[i * CC + c], y = nv[i * CC + c];
      dp += a * x; pp += x * x; dn += a * y; nn2 += y * y;
    }
    dp = bred_sum(dp, red, tid, 256);
    pp = bred_sum(pp, red, tid, 256);
    dn = bred_sum(dn, red, tid, 256);
    nn2 = bred_sum(nn2, red, tid, 256);
    if (tid == 0) {
      float cosp = dp * invn / fmaxf(sqrtf(pp), EPSV);
      float cosn = dn * invn / fmaxf(sqrtf(nn2), EPSV);
      float crov = fmaxf(MARGIN_ + cosn - cosp, 0.f);
      crovrow[i] = (nnsim[i] > 0.9f) ? crov : 0.f;
    }
  }
}

// K9 fused: block per (i,j). Wave 0: radix select (ballot-compaction, no
// same-address atomics) + rank-order into LDS (ti, tv). Then all 4 waves:
// decay with 4-row ILP (8 gathers in flight, 4 interleaved shuffle chains).
__global__ __launch_bounds__(256) void k_seldecay(const float* __restrict__ cross,
    const __half* __restrict__ L16, const float* __restrict__ lam_p,
    const int* __restrict__ vn_p, float* __restrict__ scores) {
  __shared__ unsigned int hist[256];
  __shared__ unsigned int sel[128];
  __shared__ unsigned int selk[128];
  __shared__ unsigned ti[128];
  __shared__ float tv[128];
  __shared__ float dks[128];
  int ij = blockIdx.x, tid = threadIdx.x;
  int wv = tid >> 6, lane = tid & 63;
  int K = *vn_p; if (K > 128) K = 128;
  float lam = *lam_p;

  if (wv == 0) {
    const float* row = cross + (size_t)ij * DTT;
    unsigned int v[16];
#pragma unroll
    for (int q = 0; q < 16; ++q) {
      unsigned u = __float_as_uint(row[q * 64 + lane]);
      v[q] = (u & 0x80000000u) ? ~u : (u | 0x80000000u);
    }

    unsigned prefix = 0u, pmask = 0u;
    int remaining = K;
    for (int shift = 24; shift >= 0; shift -= 8) {
#pragma unroll
      for (int q = 0; q < 4; ++q) hist[lane * 4 + q] = 0u;
      __builtin_amdgcn_wave_barrier();
#pragma unroll
      for (int q = 0; q < 16; ++q) {
        if ((v[q] & pmask) == prefix)
          atomicAdd(&hist[(v[q] >> shift) & 255u], 1u);
      }
      __builtin_amdgcn_wave_barrier();
      unsigned c0 = hist[lane * 4], c1 = hist[lane * 4 + 1];
      unsigned c2 = hist[lane * 4 + 2], c3 = hist[lane * 4 + 3];
      unsigned s = c0 + c1 + c2 + c3;
      unsigned inc = s;
#pragma unroll
      for (int off = 1; off < 64; off <<= 1) {
        unsigned t = __shfl_down(inc, off);
        if (lane + off < 64) inc += t;
      }
      unsigned exc = inc - s;
      bool found = (exc < (unsigned)remaining) && (inc >= (unsigned)remaining);
      unsigned long long bmask = __ballot(found);
      int winner = (int)(__ffsll((unsigned long long)bmask) - 1);
      unsigned packed = 0u;
      if (found) {
        unsigned c = exc;
        unsigned cc[4] = {c0, c1, c2, c3};
        int d = lane * 4;
#pragma unroll
        for (int q = 3; q >= 0; --q) {
          if (c + cc[q] >= (unsigned)remaining) { d = lane * 4 + q; break; }
          c += cc[q];
        }
        packed = ((unsigned)d << 16) | (unsigned)(remaining - (int)c);
      }
      packed = __shfl(packed, winner);
      prefix |= (packed >> 16) << shift;
      remaining = (int)(packed & 0xFFFFu);
      pmask |= 255u << shift;
    }

    // survivors via ballot-compaction (deterministic, no same-address atomics)
    {
      unsigned base = 0u;
      unsigned long long lmask = (lane == 0) ? 0ull : ((~0ull) >> (64 - lane));
#pragma unroll
      for (int q = 0; q < 16; ++q) {
        bool take = (v[q] > prefix);
        unsigned long long bm = __ballot(take);
        if (take) {
          unsigned pos = base + (unsigned)__popcll(bm & lmask);
          sel[pos] = (unsigned)(q * 64 + lane);
          selk[pos] = v[q];
        }
        base += (unsigned)__popcll(bm);
      }
    }
    __builtin_amdgcn_wave_barrier();
    {
      int base = K - remaining;
      int last = -1;
      for (int t = 0; t < remaining; ++t) {
        int mymin = 0x7FFFFFFF;
#pragma unroll
        for (int q = 0; q < 16; ++q) {
          int idx = q * 64 + lane;
          if (v[q] == prefix && idx > last && idx < mymin) mymin = idx;
        }
#pragma unroll
        for (int off = 32; off > 0; off >>= 1) mymin = min(mymin, __shfl_xor(mymin, off));
        if (lane == 0) { sel[base + t] = (unsigned)mymin; selk[base + t] = prefix; }
        last = mymin;
      }
    }
    __builtin_amdgcn_wave_barrier();

    for (int e = lane; e < K; e += 64) {
      unsigned myidx = sel[e], myk = selk[e];
      int rank = 0;
      for (int m = 0; m < K; ++m) {
        unsigned ok = selk[m];
        rank += (ok > myk || (ok == myk && sel[m] < myidx)) ? 1 : 0;
      }
      unsigned u = (myk & 0x80000000u) ? (myk & 0x7FFFFFFFu) : ~myk;
      ti[rank] = myidx;
      tv[rank] = __uint_as_float(u);
    }
  }
  __syncthreads();

  // decay: 4-row ILP per wave. Column indices are loop-invariant.
  {
    unsigned cA = ti[lane];
    unsigned cB = ti[lane + 64];   // may be garbage if K<=lane+64; never dereferenced then
    int mB = lane + 64;
    for (int rr = wv; rr < K; rr += 16) {
      int r0 = rr, r1 = rr + 4, r2 = rr + 8, r3 = rr + 12;
      float f0 = 1.f, f1 = 1.f, f2 = 1.f, f3 = 1.f;
      if (r0 < K) {
        const __half* ir = L16 + (size_t)ti[r0] * DTT;
        if (lane < r0) f0 = __half2float(ir[cA]);
        if (mB < r0) f0 *= __half2float(ir[cB]);
      }
      if (r1 < K) {
        const __half* ir = L16 + (size_t)ti[r1] * DTT;
        if (lane < r1) f1 = __half2float(ir[cA]);
        if (mB < r1) f1 *= __half2float(ir[cB]);
      }
      if (r2 < K) {
        const __half* ir = L16 + (size_t)ti[r2] * DTT;
        if (lane < r2) f2 = __half2float(ir[cA]);
        if (mB < r2) f2 *= __half2float(ir[cB]);
      }
      if (r3 < K) {
        const __half* ir = L16 + (size_t)ti[r3] * DTT;
        if (lane < r3) f3 = __half2float(ir[cA]);
        if (mB < r3) f3 *= __half2float(ir[cB]);
      }
#pragma unroll
      for (int off = 32; off > 0; off >>= 1) {
        f0 *= __shfl_xor(f0, off);
        f1 *= __shfl_xor(f1, off);
        f2 *= __shfl_xor(f2, off);
        f3 *= __shfl_xor(f3, off);
      }
      if (lane == 0) {
        dks[r0] = f0;
        if (r1 < K) dks[r1] = f1;
        if (r2 < K) dks[r2] = f2;
        if (r3 < K) dks[r3] = f3;
      }
    }
  }
  __syncthreads();

  if (wv == 0) {
    bool okA = (lane < K), okB = (lane + 64 < K);
    float vA = okA ? tv[lane] : 0.f;
    float vB = okB ? tv[lane + 64] : 0.f;
    float mx = fmaxf(okA ? lam * vA : -INFINITY, okB ? lam * vB : -INFINITY);
#pragma unroll
    for (int off = 32; off > 0; off >>= 1) mx = fmaxf(mx, __shfl_xor(mx, off));
    float eA = okA ? expf(lam * vA - mx) : 0.f;
    float eB = okB ? expf(lam * vB - mx) : 0.f;
    float se = eA + eB;
    float sc = (okA ? eA * dks[lane] * vA : 0.f) + (okB ? eB * dks[lane + 64] * vB : 0.f);
#pragma unroll
    for (int off = 32; off > 0; off >>= 1) {
      se += __shfl_xor(se, off);
      sc += __shfl_xor(sc, off);
    }
    if (lane == 0) scores[ij] = sc / se;
  }
}

// Kfinal: hinge maxima + loss
__global__ void k_final(const float* __restrict__ scores, const float* __restrict__ vasrow,
                        const float* __restrict__ crovrow, float* __restrict__ out) {
  int tid = threadIdx.x;  // 64 threads
  __shared__ float sm[BB * BB];
  __shared__ float red[64];
  for (int q = tid; q < BB * BB; q += 64) sm[q] = scores[q];
  __syncthreads();
  float di = sm[tid * BB + tid];
  float rowmax = 0.f, colmax = 0.f;
  for (int k = 0; k < BB; ++k) {
    if (k != tid) {
      rowmax = fmaxf(rowmax, fmaxf(MARGIN_ + sm[tid * BB + k] - di, 0.f));
      colmax = fmaxf(colmax, fmaxf(MARGIN_ + sm[k * BB + tid] - di, 0.f));
    }
  }
  float total = bred_sum(rowmax + colmax + vasrow[tid] + crovrow[tid], red, tid, 64);
  if (tid == 0) out[0] = total * (1.0f / BB);
}

extern "C" void kernel_launch(void* const* d_in, const int* in_sizes, int n_in,
                              void* d_out, int out_size, void* d_ws, size_t ws_size,
                              hipStream_t stream) {
  const float* videos = (const float*)d_in[0];
  const float* sentences = (const float*)d_in[1];
  const float* lam = (const float*)d_in[2];
  const float* mask = (const float*)d_in[3];
  const int* valid_num = (const int*)d_in[4];
  const float* iou_maps = (const float*)d_in[5];
  float* out = (float*)d_out;
  float* pmap = out + 1;

  float* ws = (float*)d_ws;
  float* Sn = ws;                      // 32768
  float* SnT = Sn + 32768;             // 32768
  float* SnSum = SnT + 32768;          // 64
  float* meanv = SnSum + 64;           // 65536
  float* normv = meanv + 65536;        // 65536
  float* cross = normv + 65536;        // 4194304
  float* w = cross + 4194304;          // 65536
  float* wm = w + 65536;               // 64
  float* vp = wm + 64;                 // 32768
  float* vpn = vp + 32768;             // 64
  float* vpsum = vpn + 64;             // 64
  float* nnsim = vpsum + 64;           // 64
  float* vslog = nnsim + 64;           // 65536 (becomes vsim in-place)
  float* svp = vslog + 65536;          // 64
  float* svn = svp + 64;               // 64
  float* pvb = svn + 64;               // 32768
  float* nvb = pvb + 32768;            // 32768
  float* vasrow = nvb + 32768;         // 64
  float* crovrow = vasrow + 64;        // 64
  float* scores = crovrow + 64;        // 4096
  int* nn_idx = (int*)(scores + 4096); // 64
  int* negidx = nn_idx + 64;           // 3392
  unsigned* ordi_unused = (unsigned*)(negidx + 3392);  // 524288 (slot kept)
  float* ordv_unused = (float*)(ordi_unused + 524288); // 524288 (slot kept)
  __half* L16 = (__half*)(ordv_unused + 524288);       // 1048576 halfs = 2MB
  unsigned short* SnH16 = (unsigned short*)(L16 + 1048576);  // 32768 u16
  unsigned short* SnL16 = SnH16 + 32768;                     // 32768 u16

  k_sentprep<<<1088, 256, 0, stream>>>(sentences, iou_maps, Sn, SnT, SnH16, SnL16, SnSum, L16);
  k_sim<<<64, 256, 0, stream>>>(Sn, SnT, nn_idx, negidx, nnsim);
  k_cross<<<512, 256, 0, stream>>>(videos, SnH16, SnL16, SnSum, mask, cross, meanv, normv);
  k_softmax_w<<<64, 256, 0, stream>>>(cross, meanv, pmap, w, wm);
  k_vpos<<<8192, 256, 0, stream>>>(videos, w, wm, vp);
  k_vpnorm<<<64, 256, 0, stream>>>(vp, vpn, vpsum);
  k_vsim_logits<<<256, 256, 0, stream>>>(videos, vp, vpn, vpsum, nn_idx, meanv, normv, vslog);
  k_softmax_vsim<<<64, 256, 0, stream>>>(vslog, nn_idx, meanv, mask, svp, svn);
  k_pvnv<<<8192, 256, 0, stream>>>(videos, vslog, nn_idx, mask, svp, svn, valid_num, pvb, nvb);
  k_vascrov<<<64, 256, 0, stream>>>(vp, vpn, SnT, negidx, pvb, nvb, nnsim, vasrow, crovrow);
  k_seldecay<<<4096, 256, 0, stream>>>(cross, L16, lam, valid_num, scores);
  k_final<<<1, 64, 0, stream>>>(scores, vasrow, crovrow, out);
}